// Round 1
// baseline (1046.485 us; speedup 1.0000x reference)
//
#include <hip/hip_runtime.h>
#include <math.h>

static constexpr int kN  = 50000;
static constexpr int kE  = 800000;
static constexpr int kIn = 64;
static constexpr int kC  = 32;
static constexpr int kH  = 4;
static constexpr int kHC = 128;   // H*C
static constexpr int kB  = 64;

// ---------- float ordered-int encoding for atomicMax ----------
__device__ __forceinline__ int enc_f(float f) {
    int i = __float_as_int(f);
    return (i >= 0) ? i : (i ^ 0x7FFFFFFF);
}
__device__ __forceinline__ float dec_f(int i) {
    int j = (i >= 0) ? i : (i ^ 0x7FFFFFFF);
    return __int_as_float(j);
}

// ---------- 1) dense projections q,k,v,x_r ----------
// 512 threads: thread t -> matrix (t>>7), output col (t&127); 16 nodes/block.
__global__ __launch_bounds__(512) void proj_kernel(
    const float* __restrict__ x,
    const float* __restrict__ Wq, const float* __restrict__ bq,
    const float* __restrict__ Wk, const float* __restrict__ bk,
    const float* __restrict__ Wv, const float* __restrict__ bv,
    const float* __restrict__ Wskip, const float* __restrict__ bskip,
    float* __restrict__ qb, float* __restrict__ kb,
    float* __restrict__ vb, float* __restrict__ xrb)
{
    __shared__ float4 xs[16][16];  // 16 nodes x 64 floats
    const int t  = threadIdx.x;
    const int n0 = blockIdx.x * 16;
    if (t < 256) {
        int nn = t >> 4, f4 = t & 15;
        int n = n0 + nn;
        float4 val = make_float4(0.f, 0.f, 0.f, 0.f);
        if (n < kN) val = ((const float4*)x)[(size_t)n * 16 + f4];
        xs[nn][f4] = val;
    }
    __syncthreads();
    const int mat = t >> 7;
    const int j   = t & 127;
    const float* W = (mat == 0) ? Wq : (mat == 1) ? Wk : (mat == 2) ? Wv : Wskip;
    const float* B = (mat == 0) ? bq : (mat == 1) ? bk : (mat == 2) ? bv : bskip;
    float acc[16];
    float bias = B[j];
#pragma unroll
    for (int n = 0; n < 16; ++n) acc[n] = bias;
#pragma unroll 4
    for (int ig = 0; ig < 16; ++ig) {
        float w0 = W[(ig * 4 + 0) * kHC + j];
        float w1 = W[(ig * 4 + 1) * kHC + j];
        float w2 = W[(ig * 4 + 2) * kHC + j];
        float w3 = W[(ig * 4 + 3) * kHC + j];
#pragma unroll
        for (int n = 0; n < 16; ++n) {
            float4 xv = xs[n][ig];
            acc[n] = fmaf(xv.x, w0, acc[n]);
            acc[n] = fmaf(xv.y, w1, acc[n]);
            acc[n] = fmaf(xv.z, w2, acc[n]);
            acc[n] = fmaf(xv.w, w3, acc[n]);
        }
    }
    float* outp = (mat == 0) ? qb : (mat == 1) ? kb : (mat == 2) ? vb : xrb;
#pragma unroll
    for (int n = 0; n < 16; ++n) {
        int nn = n0 + n;
        if (nn < kN) outp[(size_t)nn * kHC + j] = acc[n];
    }
}

// ---------- 2) per-edge attention logits + segment max ----------
// one wave per edge; lane l owns channels [2l, 2l+1]; head = lane>>4
__global__ __launch_bounds__(256) void edge_alpha_kernel(
    const int* __restrict__ ei, const float* __restrict__ ea,
    const float* __restrict__ qb, const float* __restrict__ kb,
    const float* __restrict__ We, const float* __restrict__ be,
    float* __restrict__ alpha_out, int* __restrict__ mbuf)
{
    int wave = (int)((blockIdx.x * (size_t)blockDim.x + threadIdx.x) >> 6);
    int lane = threadIdx.x & 63;
    if (wave >= kE) return;
    const int e = wave;
    int src = ei[e], dst = ei[kE + e];
    float a1 = ea[e];
    int hc = lane * 2;
    float2 q2 = *(const float2*)&qb[(size_t)dst * kHC + hc];
    float2 k2 = *(const float2*)&kb[(size_t)src * kHC + hc];
    float2 w2 = *(const float2*)&We[hc];
    float2 b2 = *(const float2*)&be[hc];
    float kx = fmaf(a1, w2.x, k2.x + b2.x);
    float ky = fmaf(a1, w2.y, k2.y + b2.y);
    float p = q2.x * kx + q2.y * ky;
    p += __shfl_xor(p, 1);
    p += __shfl_xor(p, 2);
    p += __shfl_xor(p, 4);
    p += __shfl_xor(p, 8);
    float alpha = p * 0.17677669529663687f;  // 1/sqrt(32)
    if ((lane & 15) == 0) {
        int h = lane >> 4;
        alpha_out[(size_t)e * kH + h] = alpha;
        atomicMax(&mbuf[dst * kH + h], enc_f(alpha));
    }
}

// ---------- 3) exp, denom, weighted aggregation ----------
__global__ __launch_bounds__(256) void edge_accum_kernel(
    const int* __restrict__ ei, const float* __restrict__ ea,
    const float* __restrict__ vb,
    const float* __restrict__ We, const float* __restrict__ be,
    const float* __restrict__ alpha_in, const int* __restrict__ mbuf,
    float* __restrict__ denom, float* __restrict__ agg)
{
    int wave = (int)((blockIdx.x * (size_t)blockDim.x + threadIdx.x) >> 6);
    int lane = threadIdx.x & 63;
    if (wave >= kE) return;
    const int e = wave;
    int src = ei[e], dst = ei[kE + e];
    float a1 = ea[e];
    int h = lane >> 4;
    float alpha = alpha_in[(size_t)e * kH + h];
    float m = dec_f(mbuf[dst * kH + h]);
    float a = expf(alpha - m);
    if ((lane & 15) == 0) unsafeAtomicAdd(&denom[dst * kH + h], a);
    int hc = lane * 2;
    float2 v2 = *(const float2*)&vb[(size_t)src * kHC + hc];
    float2 w2 = *(const float2*)&We[hc];
    float2 b2 = *(const float2*)&be[hc];
    float mx = fmaf(a1, w2.x, v2.x + b2.x) * a;
    float my = fmaf(a1, w2.y, v2.y + b2.y) * a;
    unsafeAtomicAdd(&agg[(size_t)dst * kHC + hc], mx);
    unsafeAtomicAdd(&agg[(size_t)dst * kHC + hc + 1], my);
}

// ---------- 4) normalize, beta-gate, post-linear + relu ----------
__global__ __launch_bounds__(128) void node_final_kernel(
    const float* __restrict__ agg, const float* __restrict__ denom,
    const float* __restrict__ xr,
    const float* __restrict__ Wbeta, const float* __restrict__ Wlin,
    const float* __restrict__ blin,
    float* __restrict__ hbuf)
{
    __shared__ float wl[kHC * kC];   // 16 KB
    __shared__ float wb[3 * kHC];
    __shared__ float osh[kHC];
    __shared__ float red[2];
    __shared__ float hred[4][kC];
    const int t = threadIdx.x;
    for (int i = t; i < kHC * kC; i += 128) wl[i] = Wlin[i];
    for (int i = t; i < 3 * kHC; i += 128) wb[i] = Wbeta[i];
    __syncthreads();
    for (int n = blockIdx.x; n < kN; n += gridDim.x) {
        float val = agg[(size_t)n * kHC + t];
        float d = denom[n * kH + (t >> 5)];
        val /= fmaxf(d, 1e-16f);
        float xrv = xr[(size_t)n * kHC + t];
        float part = wb[t] * val + wb[kHC + t] * xrv + wb[2 * kHC + t] * (val - xrv);
#pragma unroll
        for (int s = 1; s < 64; s <<= 1) part += __shfl_xor(part, s);
        if ((t & 63) == 0) red[t >> 6] = part;
        __syncthreads();
        float s = red[0] + red[1];
        float beta = 1.f / (1.f + expf(-s));
        float o = beta * xrv + (1.f - beta) * val;
        osh[t] = o;
        __syncthreads();
        int c = t & 31, qt = t >> 5;
        float hp = 0.f;
#pragma unroll
        for (int jj = 0; jj < 32; ++jj)
            hp = fmaf(osh[qt * 32 + jj], wl[(qt * 32 + jj) * kC + c], hp);
        hred[qt][c] = hp;
        __syncthreads();
        if (t < kC) {
            float hv = hred[0][t] + hred[1][t] + hred[2][t] + hred[3][t] + blin[t];
            hbuf[(size_t)n * kC + t] = fmaxf(hv, 0.f);
        }
        __syncthreads();
    }
}

// ---------- 5) GraphNorm: one block per graph (batch_index sorted) ----------
__global__ __launch_bounds__(256) void graphnorm_kernel(
    const float* __restrict__ hbuf, const int* __restrict__ batch,
    const float* __restrict__ gw, const float* __restrict__ gb,
    const float* __restrict__ gms,
    float* __restrict__ out)
{
    const int g = blockIdx.x;
    const int t = threadIdx.x;
    __shared__ int se[2];
    __shared__ float sums[8][kC];
    __shared__ float meansh[kC], rstdsh[kC];
    if (t < 2) {
        int target = g + t;
        int lo = 0, hi = kN;
        while (lo < hi) { int mid = (lo + hi) >> 1; if (batch[mid] < target) lo = mid + 1; else hi = mid; }
        se[t] = lo;
    }
    __syncthreads();
    int start = se[0], end = se[1];
    float cnt = fmaxf((float)(end - start), 1.f);
    int c = t & 31, r = t >> 5;
    float acc = 0.f;
    for (int n = start + r; n < end; n += 8) acc += hbuf[(size_t)n * kC + c];
    sums[r][c] = acc;
    __syncthreads();
    if (t < kC) {
        float s = 0.f;
#pragma unroll
        for (int i = 0; i < 8; ++i) s += sums[i][t];
        meansh[t] = s / cnt * gms[t];  // mean * gn_mean_scale
    }
    __syncthreads();
    float msc = meansh[c];
    acc = 0.f;
    for (int n = start + r; n < end; n += 8) {
        float dd = hbuf[(size_t)n * kC + c] - msc;
        acc = fmaf(dd, dd, acc);
    }
    sums[r][c] = acc;
    __syncthreads();
    if (t < kC) {
        float s2 = 0.f;
#pragma unroll
        for (int i = 0; i < 8; ++i) s2 += sums[i][t];
        rstdsh[t] = rsqrtf(s2 / cnt + 1e-5f);
    }
    __syncthreads();
    float rstd = rstdsh[c], w = gw[c], b = gb[c];
    for (int n = start + r; n < end; n += 8) {
        float dd = hbuf[(size_t)n * kC + c] - msc;
        out[(size_t)n * kC + c] = fmaf(w * dd, rstd, b);
    }
}

extern "C" void kernel_launch(void* const* d_in, const int* in_sizes, int n_in,
                              void* d_out, int out_size, void* d_ws, size_t ws_size,
                              hipStream_t stream) {
    (void)in_sizes; (void)n_in; (void)out_size; (void)ws_size;
    const float* x     = (const float*)d_in[0];
    const int*   ei    = (const int*)d_in[1];
    const float* ea    = (const float*)d_in[2];
    const int*   batch = (const int*)d_in[3];
    const float* Wq    = (const float*)d_in[4];
    const float* bq    = (const float*)d_in[5];
    const float* Wk    = (const float*)d_in[6];
    const float* bk    = (const float*)d_in[7];
    const float* Wv    = (const float*)d_in[8];
    const float* bv    = (const float*)d_in[9];
    const float* We    = (const float*)d_in[10];
    const float* be    = (const float*)d_in[11];
    const float* Wskip = (const float*)d_in[12];
    const float* bskip = (const float*)d_in[13];
    const float* Wbeta = (const float*)d_in[14];
    const float* Wlin  = (const float*)d_in[15];
    const float* blin  = (const float*)d_in[16];
    const float* gw    = (const float*)d_in[17];
    const float* gb    = (const float*)d_in[18];
    const float* gms   = (const float*)d_in[19];
    float* out = (float*)d_out;

    float* ws = (float*)d_ws;
    const size_t NQ = (size_t)kN * kHC;          // 6.4M floats
    float* qb    = ws;
    float* kb    = qb + NQ;
    float* vb    = kb + NQ;
    float* xrb   = vb + NQ;
    float* agg   = xrb + NQ;
    float* alpha = agg + NQ;                     // E*H
    float* denom = alpha + (size_t)kE * kH;      // N*H
    int*   mbuf  = (int*)(denom + (size_t)kN * kH);
    float* hbuf  = (float*)(mbuf + (size_t)kN * kH);

    hipMemsetAsync(agg, 0, NQ * sizeof(float), stream);
    hipMemsetAsync(denom, 0, (size_t)kN * kH * sizeof(float), stream);
    // 0x80808080 decodes to ~-3.4e38: a safe "-inf" for the encoded max
    hipMemsetAsync(mbuf, 0x80, (size_t)kN * kH * sizeof(int), stream);

    proj_kernel<<<(kN + 15) / 16, 512, 0, stream>>>(
        x, Wq, bq, Wk, bk, Wv, bv, Wskip, bskip, qb, kb, vb, xrb);
    edge_alpha_kernel<<<(kE + 3) / 4, 256, 0, stream>>>(
        ei, ea, qb, kb, We, be, alpha, mbuf);
    edge_accum_kernel<<<(kE + 3) / 4, 256, 0, stream>>>(
        ei, ea, vb, We, be, alpha, mbuf, denom, agg);
    node_final_kernel<<<1024, 128, 0, stream>>>(
        agg, denom, xrb, Wbeta, Wlin, blin, hbuf);
    graphnorm_kernel<<<kB, 256, 0, stream>>>(
        hbuf, batch, gw, gb, gms, out);
}

// Round 2
// 458.638 us; speedup vs baseline: 2.2817x; 2.2817x over previous
//
#include <hip/hip_runtime.h>
#include <math.h>

static constexpr int kN  = 50000;
static constexpr int kE  = 800000;
static constexpr int kIn = 64;
static constexpr int kC  = 32;
static constexpr int kH  = 4;
static constexpr int kHC = 128;   // H*C
static constexpr int kB  = 64;

// ---------- 1) dense projections q,k,v,x_r ----------
__global__ __launch_bounds__(512) void proj_kernel(
    const float* __restrict__ x,
    const float* __restrict__ Wq, const float* __restrict__ bq,
    const float* __restrict__ Wk, const float* __restrict__ bk,
    const float* __restrict__ Wv, const float* __restrict__ bv,
    const float* __restrict__ Wskip, const float* __restrict__ bskip,
    float* __restrict__ qb, float* __restrict__ kb,
    float* __restrict__ vb, float* __restrict__ xrb)
{
    __shared__ float4 xs[16][16];  // 16 nodes x 64 floats
    const int t  = threadIdx.x;
    const int n0 = blockIdx.x * 16;
    if (t < 256) {
        int nn = t >> 4, f4 = t & 15;
        int n = n0 + nn;
        float4 val = make_float4(0.f, 0.f, 0.f, 0.f);
        if (n < kN) val = ((const float4*)x)[(size_t)n * 16 + f4];
        xs[nn][f4] = val;
    }
    __syncthreads();
    const int mat = t >> 7;
    const int j   = t & 127;
    const float* W = (mat == 0) ? Wq : (mat == 1) ? Wk : (mat == 2) ? Wv : Wskip;
    const float* B = (mat == 0) ? bq : (mat == 1) ? bk : (mat == 2) ? bv : bskip;
    float acc[16];
    float bias = B[j];
#pragma unroll
    for (int n = 0; n < 16; ++n) acc[n] = bias;
#pragma unroll 4
    for (int ig = 0; ig < 16; ++ig) {
        float w0 = W[(ig * 4 + 0) * kHC + j];
        float w1 = W[(ig * 4 + 1) * kHC + j];
        float w2 = W[(ig * 4 + 2) * kHC + j];
        float w3 = W[(ig * 4 + 3) * kHC + j];
#pragma unroll
        for (int n = 0; n < 16; ++n) {
            float4 xv = xs[n][ig];
            acc[n] = fmaf(xv.x, w0, acc[n]);
            acc[n] = fmaf(xv.y, w1, acc[n]);
            acc[n] = fmaf(xv.z, w2, acc[n]);
            acc[n] = fmaf(xv.w, w3, acc[n]);
        }
    }
    float* outp = (mat == 0) ? qb : (mat == 1) ? kb : (mat == 2) ? vb : xrb;
#pragma unroll
    for (int n = 0; n < 16; ++n) {
        int nn = n0 + n;
        if (nn < kN) outp[(size_t)nn * kHC + j] = acc[n];
    }
}

// ---------- 2) CSR build: histogram ----------
__global__ __launch_bounds__(256) void hist_kernel(
    const int* __restrict__ ei, int* __restrict__ deg)
{
    int i = blockIdx.x * 256 + threadIdx.x;
    if (i < kE) atomicAdd(&deg[ei[kE + i]], 1);
}

// ---------- 3) CSR build: single-block exclusive scan ----------
__global__ __launch_bounds__(1024) void scan_kernel(
    const int* __restrict__ deg, int* __restrict__ rowptr, int* __restrict__ cursor)
{
    __shared__ int ssum[1024];
    const int t = threadIdx.x;
    const int CH = (kN + 1023) / 1024;   // 49
    int begi = t * CH;
    int endi = begi + CH; if (endi > kN) endi = kN;
    if (begi > kN) begi = kN;
    int s = 0;
    for (int i = begi; i < endi; ++i) s += deg[i];
    ssum[t] = s;
    __syncthreads();
    for (int off = 1; off < 1024; off <<= 1) {
        int v = (t >= off) ? ssum[t - off] : 0;
        __syncthreads();
        ssum[t] += v;
        __syncthreads();
    }
    int run = (t == 0) ? 0 : ssum[t - 1];
    for (int i = begi; i < endi; ++i) {
        rowptr[i] = run; cursor[i] = run;
        run += deg[i];
    }
    if (t == 1023) rowptr[kN] = ssum[1023];
}

// ---------- 4) CSR build: scatter (src, edge_attr) grouped by dst ----------
__global__ __launch_bounds__(256) void scatter_kernel(
    const int* __restrict__ ei, const float* __restrict__ ea,
    int* __restrict__ cursor,
    int* __restrict__ csr_src, float* __restrict__ csr_ea)
{
    int i = blockIdx.x * 256 + threadIdx.x;
    if (i >= kE) return;
    int dst = ei[kE + i];
    int slot = atomicAdd(&cursor[dst], 1);
    csr_src[slot] = ei[i];
    csr_ea[slot]  = ea[i];
}

// ---------- 5) per-node online-softmax attention + full epilogue ----------
// one wave per node; lane l owns channels [2l, 2l+1]; head = lane>>4
__global__ __launch_bounds__(256) void node_attn_kernel(
    const int* __restrict__ rowptr,
    const int* __restrict__ csr_src, const float* __restrict__ csr_ea,
    const float* __restrict__ qb, const float* __restrict__ kb,
    const float* __restrict__ vb, const float* __restrict__ xrb,
    const float* __restrict__ We, const float* __restrict__ be,
    const float* __restrict__ Wbeta, const float* __restrict__ Wlin,
    const float* __restrict__ blin,
    float* __restrict__ hbuf)
{
    __shared__ float wlS[kHC * kC];    // 16 KB
    __shared__ float wbS[3 * kHC];     // 1.5 KB
    __shared__ float oshS[4][kHC];     // 2 KB
    const int t    = threadIdx.x;
    const int wv   = t >> 6;
    const int lane = t & 63;
    for (int i = t; i < kHC * kC; i += 256) wlS[i] = Wlin[i];
    for (int i = t; i < 3 * kHC; i += 256) wbS[i] = Wbeta[i];
    __syncthreads();

    const int node = blockIdx.x * 4 + wv;   // grid covers exactly kN
    const int hc = lane * 2;
    const float2 q2 = *(const float2*)&qb[(size_t)node * kHC + hc];
    const float2 w2 = *(const float2*)&We[hc];
    const float2 b2 = *(const float2*)&be[hc];

    float m = -3.0e38f, ssum = 0.f, ax = 0.f, ay = 0.f;
    const int beg = rowptr[node], end = rowptr[node + 1];

    int e = beg;
    for (; e + 1 < end; e += 2) {
        int  s0 = csr_src[e],     s1 = csr_src[e + 1];
        float a0 = csr_ea[e],     a1 = csr_ea[e + 1];
        float2 k20 = *(const float2*)&kb[(size_t)s0 * kHC + hc];
        float2 v20 = *(const float2*)&vb[(size_t)s0 * kHC + hc];
        float2 k21 = *(const float2*)&kb[(size_t)s1 * kHC + hc];
        float2 v21 = *(const float2*)&vb[(size_t)s1 * kHC + hc];
        float kx0 = fmaf(a0, w2.x, k20.x + b2.x);
        float ky0 = fmaf(a0, w2.y, k20.y + b2.y);
        float kx1 = fmaf(a1, w2.x, k21.x + b2.x);
        float ky1 = fmaf(a1, w2.y, k21.y + b2.y);
        float p0 = q2.x * kx0 + q2.y * ky0;
        float p1 = q2.x * kx1 + q2.y * ky1;
        p0 += __shfl_xor(p0, 1);  p1 += __shfl_xor(p1, 1);
        p0 += __shfl_xor(p0, 2);  p1 += __shfl_xor(p1, 2);
        p0 += __shfl_xor(p0, 4);  p1 += __shfl_xor(p1, 4);
        p0 += __shfl_xor(p0, 8);  p1 += __shfl_xor(p1, 8);
        float al0 = p0 * 0.17677669529663687f;
        float al1 = p1 * 0.17677669529663687f;
        float vx0 = fmaf(a0, w2.x, v20.x + b2.x);
        float vy0 = fmaf(a0, w2.y, v20.y + b2.y);
        float vx1 = fmaf(a1, w2.x, v21.x + b2.x);
        float vy1 = fmaf(a1, w2.y, v21.y + b2.y);
        // online update edge 0
        float mn = fmaxf(m, al0);
        float sc = __expf(m - mn);
        float w  = __expf(al0 - mn);
        ssum = ssum * sc + w;
        ax = fmaf(ax, sc, w * vx0);
        ay = fmaf(ay, sc, w * vy0);
        m = mn;
        // online update edge 1
        mn = fmaxf(m, al1);
        sc = __expf(m - mn);
        w  = __expf(al1 - mn);
        ssum = ssum * sc + w;
        ax = fmaf(ax, sc, w * vx1);
        ay = fmaf(ay, sc, w * vy1);
        m = mn;
    }
    if (e < end) {
        int  s0 = csr_src[e];
        float a0 = csr_ea[e];
        float2 k20 = *(const float2*)&kb[(size_t)s0 * kHC + hc];
        float2 v20 = *(const float2*)&vb[(size_t)s0 * kHC + hc];
        float kx0 = fmaf(a0, w2.x, k20.x + b2.x);
        float ky0 = fmaf(a0, w2.y, k20.y + b2.y);
        float p0 = q2.x * kx0 + q2.y * ky0;
        p0 += __shfl_xor(p0, 1);
        p0 += __shfl_xor(p0, 2);
        p0 += __shfl_xor(p0, 4);
        p0 += __shfl_xor(p0, 8);
        float al0 = p0 * 0.17677669529663687f;
        float vx0 = fmaf(a0, w2.x, v20.x + b2.x);
        float vy0 = fmaf(a0, w2.y, v20.y + b2.y);
        float mn = fmaxf(m, al0);
        float sc = __expf(m - mn);
        float w  = __expf(al0 - mn);
        ssum = ssum * sc + w;
        ax = fmaf(ax, sc, w * vx0);
        ay = fmaf(ay, sc, w * vy0);
        m = mn;
    }

    // ---- epilogue: normalize, beta-gate, 128->32 linear + relu ----
    float rcp = 1.f / fmaxf(ssum, 1e-16f);
    float val0 = ax * rcp, val1 = ay * rcp;
    float2 xr2 = *(const float2*)&xrb[(size_t)node * kHC + hc];
    float part = wbS[hc] * val0 + wbS[hc + 1] * val1
               + wbS[kHC + hc] * xr2.x + wbS[kHC + hc + 1] * xr2.y
               + wbS[2 * kHC + hc] * (val0 - xr2.x)
               + wbS[2 * kHC + hc + 1] * (val1 - xr2.y);
#pragma unroll
    for (int sft = 1; sft < 64; sft <<= 1) part += __shfl_xor(part, sft);
    float beta = 1.f / (1.f + __expf(-part));
    float o0 = beta * xr2.x + (1.f - beta) * val0;
    float o1 = beta * xr2.y + (1.f - beta) * val1;
    oshS[wv][hc] = o0;
    oshS[wv][hc + 1] = o1;
    __syncthreads();
    int c = lane & 31, half = lane >> 5;
    float hp = 0.f;
#pragma unroll
    for (int jj = 0; jj < 64; ++jj) {
        int j = half * 64 + jj;
        hp = fmaf(oshS[wv][j], wlS[j * kC + c], hp);
    }
    hp += __shfl_xor(hp, 32);
    if (lane < 32) {
        float hv = hp + blin[c];
        hbuf[(size_t)node * kC + c] = fmaxf(hv, 0.f);
    }
}

// ---------- 6) GraphNorm: one block per graph (batch_index sorted) ----------
__global__ __launch_bounds__(256) void graphnorm_kernel(
    const float* __restrict__ hbuf, const int* __restrict__ batch,
    const float* __restrict__ gw, const float* __restrict__ gb,
    const float* __restrict__ gms,
    float* __restrict__ out)
{
    const int g = blockIdx.x;
    const int t = threadIdx.x;
    __shared__ int se[2];
    __shared__ float sums[8][kC];
    __shared__ float meansh[kC], rstdsh[kC];
    if (t < 2) {
        int target = g + t;
        int lo = 0, hi = kN;
        while (lo < hi) { int mid = (lo + hi) >> 1; if (batch[mid] < target) lo = mid + 1; else hi = mid; }
        se[t] = lo;
    }
    __syncthreads();
    int start = se[0], end = se[1];
    float cnt = fmaxf((float)(end - start), 1.f);
    int c = t & 31, r = t >> 5;
    float acc = 0.f;
    for (int n = start + r; n < end; n += 8) acc += hbuf[(size_t)n * kC + c];
    sums[r][c] = acc;
    __syncthreads();
    if (t < kC) {
        float s = 0.f;
#pragma unroll
        for (int i = 0; i < 8; ++i) s += sums[i][t];
        meansh[t] = s / cnt * gms[t];
    }
    __syncthreads();
    float msc = meansh[c];
    acc = 0.f;
    for (int n = start + r; n < end; n += 8) {
        float dd = hbuf[(size_t)n * kC + c] - msc;
        acc = fmaf(dd, dd, acc);
    }
    sums[r][c] = acc;
    __syncthreads();
    if (t < kC) {
        float s2 = 0.f;
#pragma unroll
        for (int i = 0; i < 8; ++i) s2 += sums[i][t];
        rstdsh[t] = rsqrtf(s2 / cnt + 1e-5f);
    }
    __syncthreads();
    float rstd = rstdsh[c], w = gw[c], b = gb[c];
    for (int n = start + r; n < end; n += 8) {
        float dd = hbuf[(size_t)n * kC + c] - msc;
        out[(size_t)n * kC + c] = fmaf(w * dd, rstd, b);
    }
}

extern "C" void kernel_launch(void* const* d_in, const int* in_sizes, int n_in,
                              void* d_out, int out_size, void* d_ws, size_t ws_size,
                              hipStream_t stream) {
    (void)in_sizes; (void)n_in; (void)out_size; (void)ws_size;
    const float* x     = (const float*)d_in[0];
    const int*   ei    = (const int*)d_in[1];
    const float* ea    = (const float*)d_in[2];
    const int*   batch = (const int*)d_in[3];
    const float* Wq    = (const float*)d_in[4];
    const float* bq    = (const float*)d_in[5];
    const float* Wk    = (const float*)d_in[6];
    const float* bk    = (const float*)d_in[7];
    const float* Wv    = (const float*)d_in[8];
    const float* bv    = (const float*)d_in[9];
    const float* We    = (const float*)d_in[10];
    const float* be    = (const float*)d_in[11];
    const float* Wskip = (const float*)d_in[12];
    const float* bskip = (const float*)d_in[13];
    const float* Wbeta = (const float*)d_in[14];
    const float* Wlin  = (const float*)d_in[15];
    const float* blin  = (const float*)d_in[16];
    const float* gw    = (const float*)d_in[17];
    const float* gb    = (const float*)d_in[18];
    const float* gms   = (const float*)d_in[19];
    float* out = (float*)d_out;

    char* ws = (char*)d_ws;
    const size_t NQ = (size_t)kN * kHC;
    float* qb      = (float*)ws;                 ws += NQ * 4;
    float* kb      = (float*)ws;                 ws += NQ * 4;
    float* vb      = (float*)ws;                 ws += NQ * 4;
    float* xrb     = (float*)ws;                 ws += NQ * 4;
    int*   deg     = (int*)ws;                   ws += (size_t)kN * 4;
    int*   cursor  = (int*)ws;                   ws += (size_t)kN * 4;
    int*   rowptr  = (int*)ws;                   ws += (size_t)(kN + 1) * 4;
    int*   csr_src = (int*)ws;                   ws += (size_t)kE * 4;
    float* csr_ea  = (float*)ws;                 ws += (size_t)kE * 4;
    float* hbuf    = (float*)ws;                 ws += (size_t)kN * kC * 4;

    hipMemsetAsync(deg, 0, (size_t)kN * 4, stream);

    proj_kernel<<<(kN + 15) / 16, 512, 0, stream>>>(
        x, Wq, bq, Wk, bk, Wv, bv, Wskip, bskip, qb, kb, vb, xrb);
    hist_kernel<<<(kE + 255) / 256, 256, 0, stream>>>(ei, deg);
    scan_kernel<<<1, 1024, 0, stream>>>(deg, rowptr, cursor);
    scatter_kernel<<<(kE + 255) / 256, 256, 0, stream>>>(ei, ea, cursor, csr_src, csr_ea);
    node_attn_kernel<<<kN / 4, 256, 0, stream>>>(
        rowptr, csr_src, csr_ea, qb, kb, vb, xrb, We, be, Wbeta, Wlin, blin, hbuf);
    graphnorm_kernel<<<kB, 256, 0, stream>>>(
        hbuf, batch, gw, gb, gms, out);
}

// Round 3
// 372.194 us; speedup vs baseline: 2.8117x; 1.2323x over previous
//
#include <hip/hip_runtime.h>
#include <math.h>

static constexpr int kN  = 50000;
static constexpr int kE  = 800000;
static constexpr int kC  = 32;
static constexpr int kH  = 4;
static constexpr int kHC = 128;   // H*C
static constexpr int kB  = 64;
static constexpr int kNB = (kN + 255) / 256;   // 196 scan blocks

__device__ __forceinline__ float bf2f(unsigned short u) {
    return __uint_as_float(((unsigned)u) << 16);
}
__device__ __forceinline__ unsigned short f2bf(float f) {
    unsigned u = __float_as_uint(f);
    unsigned r = (u + 0x7FFFu + ((u >> 16) & 1u)) >> 16;
    return (unsigned short)r;
}

// ---------- 1) dense projections: q (f32), k|v (bf16 packed), x_r (f32) ----------
__global__ __launch_bounds__(512) void proj_kernel(
    const float* __restrict__ x,
    const float* __restrict__ Wq, const float* __restrict__ bq,
    const float* __restrict__ Wk, const float* __restrict__ bk,
    const float* __restrict__ Wv, const float* __restrict__ bv,
    const float* __restrict__ Wskip, const float* __restrict__ bskip,
    float* __restrict__ qb, unsigned short* __restrict__ kvb,
    float* __restrict__ xrb)
{
    __shared__ float4 xs[16][16];  // 16 nodes x 64 floats
    const int t  = threadIdx.x;
    const int n0 = blockIdx.x * 16;
    if (t < 256) {
        int nn = t >> 4, f4 = t & 15;
        int n = n0 + nn;
        float4 val = make_float4(0.f, 0.f, 0.f, 0.f);
        if (n < kN) val = ((const float4*)x)[(size_t)n * 16 + f4];
        xs[nn][f4] = val;
    }
    __syncthreads();
    const int mat = t >> 7;
    const int j   = t & 127;
    const float* W = (mat == 0) ? Wq : (mat == 1) ? Wk : (mat == 2) ? Wv : Wskip;
    const float* B = (mat == 0) ? bq : (mat == 1) ? bk : (mat == 2) ? bv : bskip;
    float acc[16];
    float bias = B[j];
#pragma unroll
    for (int n = 0; n < 16; ++n) acc[n] = bias;
#pragma unroll 4
    for (int ig = 0; ig < 16; ++ig) {
        float w0 = W[(ig * 4 + 0) * kHC + j];
        float w1 = W[(ig * 4 + 1) * kHC + j];
        float w2 = W[(ig * 4 + 2) * kHC + j];
        float w3 = W[(ig * 4 + 3) * kHC + j];
#pragma unroll
        for (int n = 0; n < 16; ++n) {
            float4 xv = xs[n][ig];
            acc[n] = fmaf(xv.x, w0, acc[n]);
            acc[n] = fmaf(xv.y, w1, acc[n]);
            acc[n] = fmaf(xv.z, w2, acc[n]);
            acc[n] = fmaf(xv.w, w3, acc[n]);
        }
    }
#pragma unroll
    for (int n = 0; n < 16; ++n) {
        int nn = n0 + n;
        if (nn >= kN) continue;
        if (mat == 0)      qb[(size_t)nn * kHC + j] = acc[n];
        else if (mat == 1) kvb[(size_t)nn * 256 + j] = f2bf(acc[n]);
        else if (mat == 2) kvb[(size_t)nn * 256 + 128 + j] = f2bf(acc[n]);
        else               xrb[(size_t)nn * kHC + j] = acc[n];
    }
}

// ---------- 2) CSR: histogram ----------
__global__ __launch_bounds__(256) void hist_kernel(
    const int* __restrict__ ei, int* __restrict__ deg)
{
    int i = blockIdx.x * 256 + threadIdx.x;
    if (i < kE) atomicAdd(&deg[ei[kE + i]], 1);
}

// ---------- 3) CSR: hierarchical scan (A: block sums, B: scan sums, C: offsets) ----
__global__ __launch_bounds__(256) void scanA_kernel(
    const int* __restrict__ deg, int* __restrict__ bsum)
{
    int i = blockIdx.x * 256 + threadIdx.x;
    int v = (i < kN) ? deg[i] : 0;
#pragma unroll
    for (int s = 1; s < 64; s <<= 1) v += __shfl_xor(v, s);
    __shared__ int sh[4];
    if ((threadIdx.x & 63) == 0) sh[threadIdx.x >> 6] = v;
    __syncthreads();
    if (threadIdx.x == 0) bsum[blockIdx.x] = sh[0] + sh[1] + sh[2] + sh[3];
}

__global__ __launch_bounds__(256) void scanB_kernel(
    const int* __restrict__ bsum, int* __restrict__ bofs, int* __restrict__ rowptr)
{
    __shared__ int sh[256];
    int t = threadIdx.x;
    int v = (t < kNB) ? bsum[t] : 0;
    sh[t] = v; __syncthreads();
    for (int off = 1; off < 256; off <<= 1) {
        int u = (t >= off) ? sh[t - off] : 0;
        __syncthreads();
        sh[t] += u;
        __syncthreads();
    }
    if (t < kNB) bofs[t] = sh[t] - v;
    if (t == kNB - 1) rowptr[kN] = sh[t];
}

__global__ __launch_bounds__(256) void scanC_kernel(
    const int* __restrict__ deg, const int* __restrict__ bofs,
    int* __restrict__ rowptr, int* __restrict__ cursor)
{
    __shared__ int sh[256];
    int t = threadIdx.x, i = blockIdx.x * 256 + t;
    int v = (i < kN) ? deg[i] : 0;
    sh[t] = v; __syncthreads();
    for (int off = 1; off < 256; off <<= 1) {
        int u = (t >= off) ? sh[t - off] : 0;
        __syncthreads();
        sh[t] += u;
        __syncthreads();
    }
    if (i < kN) {
        int ex = sh[t] - v + bofs[blockIdx.x];
        rowptr[i] = ex;
        cursor[i] = ex;
    }
}

// ---------- 4) CSR: scatter packed (src, edge_attr) ----------
__global__ __launch_bounds__(256) void scatter_kernel(
    const int* __restrict__ ei, const float* __restrict__ ea,
    int* __restrict__ cursor, int2* __restrict__ csr)
{
    int i = blockIdx.x * 256 + threadIdx.x;
    if (i >= kE) return;
    int dst = ei[kE + i];
    int slot = atomicAdd(&cursor[dst], 1);
    csr[slot] = make_int2(ei[i], __float_as_int(ea[i]));
}

// ---------- 5) per-node online-softmax attention + epilogue ----------
// one wave per node (grid-stride); lane l owns channels [2l,2l+1]; head = lane>>4
__global__ __launch_bounds__(256) void node_attn_kernel(
    const int* __restrict__ rowptr, const int2* __restrict__ csr,
    const float* __restrict__ qb, const unsigned short* __restrict__ kvb,
    const float* __restrict__ xrb,
    const float* __restrict__ We, const float* __restrict__ be,
    const float* __restrict__ Wbeta, const float* __restrict__ Wlin,
    const float* __restrict__ blin, float* __restrict__ hbuf)
{
    __shared__ float wlS[kHC * kC];   // 16 KB
    __shared__ float wbS[3 * kHC];
    __shared__ float oshS[4][kHC];
    const int t = threadIdx.x, wv = t >> 6, lane = t & 63;
    for (int i = t; i < kHC * kC; i += 256) wlS[i] = Wlin[i];
    for (int i = t; i < 3 * kHC; i += 256) wbS[i] = Wbeta[i];
    __syncthreads();

    const int hc = lane * 2;
    const float2 we2 = *(const float2*)&We[hc];
    const float2 be2 = *(const float2*)&be[hc];
    const float wb0 = wbS[hc], wb1 = wbS[hc + 1];
    const float wb2 = wbS[kHC + hc], wb3 = wbS[kHC + hc + 1];
    const float wb4 = wbS[2 * kHC + hc], wb5 = wbS[2 * kHC + hc + 1];
    const float blc = blin[lane & 31];
    const float A = 0.17677669529663687f;   // 1/sqrt(32)
    const int nwv = gridDim.x * 4;

    for (int node = blockIdx.x * 4 + wv; node < kN; node += nwv) {
        const float2 q2 = *(const float2*)&qb[(size_t)node * kHC + hc];
        // per-head scalars: q·We_h, q·be_h
        float qw = q2.x * we2.x + q2.y * we2.y;
        float qe = q2.x * be2.x + q2.y * be2.y;
        qw += __shfl_xor(qw, 1); qe += __shfl_xor(qe, 1);
        qw += __shfl_xor(qw, 2); qe += __shfl_xor(qe, 2);
        qw += __shfl_xor(qw, 4); qe += __shfl_xor(qe, 4);
        qw += __shfl_xor(qw, 8); qe += __shfl_xor(qe, 8);
        const float qwA = qw * A, qbA = qe * A;

        float mx = -3.0e38f, ss = 0.f, swa = 0.f, ax = 0.f, ay = 0.f;
        const int beg = rowptr[node], end = rowptr[node + 1];
        int e = beg;
        for (; e + 3 < end; e += 4) {
            int2 c0 = csr[e], c1 = csr[e + 1], c2 = csr[e + 2], c3 = csr[e + 3];
            const ushort2* r0 = (const ushort2*)(kvb + (size_t)c0.x * 256);
            const ushort2* r1 = (const ushort2*)(kvb + (size_t)c1.x * 256);
            const ushort2* r2 = (const ushort2*)(kvb + (size_t)c2.x * 256);
            const ushort2* r3 = (const ushort2*)(kvb + (size_t)c3.x * 256);
            ushort2 k0 = r0[lane], k1 = r1[lane], k2 = r2[lane], k3 = r3[lane];
            ushort2 v0 = r0[64 + lane], v1 = r1[64 + lane], v2 = r2[64 + lane], v3 = r3[64 + lane];
            float a0 = __int_as_float(c0.y), a1 = __int_as_float(c1.y);
            float a2 = __int_as_float(c2.y), a3 = __int_as_float(c3.y);
            float p0 = fmaf(q2.y, bf2f(k0.y), q2.x * bf2f(k0.x));
            float p1 = fmaf(q2.y, bf2f(k1.y), q2.x * bf2f(k1.x));
            float p2 = fmaf(q2.y, bf2f(k2.y), q2.x * bf2f(k2.x));
            float p3 = fmaf(q2.y, bf2f(k3.y), q2.x * bf2f(k3.x));
            p0 += __shfl_xor(p0, 1); p1 += __shfl_xor(p1, 1); p2 += __shfl_xor(p2, 1); p3 += __shfl_xor(p3, 1);
            p0 += __shfl_xor(p0, 2); p1 += __shfl_xor(p1, 2); p2 += __shfl_xor(p2, 2); p3 += __shfl_xor(p3, 2);
            p0 += __shfl_xor(p0, 4); p1 += __shfl_xor(p1, 4); p2 += __shfl_xor(p2, 4); p3 += __shfl_xor(p3, 4);
            p0 += __shfl_xor(p0, 8); p1 += __shfl_xor(p1, 8); p2 += __shfl_xor(p2, 8); p3 += __shfl_xor(p3, 8);
            float l0 = fmaf(p0, A, fmaf(a0, qwA, qbA));
            float l1 = fmaf(p1, A, fmaf(a1, qwA, qbA));
            float l2 = fmaf(p2, A, fmaf(a2, qwA, qbA));
            float l3 = fmaf(p3, A, fmaf(a3, qwA, qbA));
            float bm = fmaxf(fmaxf(fmaxf(l0, l1), fmaxf(l2, l3)), mx);
            float sc = __expf(mx - bm);
            float e0 = __expf(l0 - bm), e1 = __expf(l1 - bm);
            float e2 = __expf(l2 - bm), e3 = __expf(l3 - bm);
            ss  = fmaf(ss , sc, (e0 + e1) + (e2 + e3));
            swa = fmaf(swa, sc, fmaf(e0, a0, fmaf(e1, a1, fmaf(e2, a2, e3 * a3))));
            ax  = fmaf(ax , sc, fmaf(e0, bf2f(v0.x), fmaf(e1, bf2f(v1.x), fmaf(e2, bf2f(v2.x), e3 * bf2f(v3.x)))));
            ay  = fmaf(ay , sc, fmaf(e0, bf2f(v0.y), fmaf(e1, bf2f(v1.y), fmaf(e2, bf2f(v2.y), e3 * bf2f(v3.y)))));
            mx = bm;
        }
        for (; e < end; ++e) {
            int2 c0 = csr[e];
            const ushort2* r0 = (const ushort2*)(kvb + (size_t)c0.x * 256);
            ushort2 k0 = r0[lane], v0 = r0[64 + lane];
            float a0 = __int_as_float(c0.y);
            float p0 = fmaf(q2.y, bf2f(k0.y), q2.x * bf2f(k0.x));
            p0 += __shfl_xor(p0, 1); p0 += __shfl_xor(p0, 2);
            p0 += __shfl_xor(p0, 4); p0 += __shfl_xor(p0, 8);
            float l0 = fmaf(p0, A, fmaf(a0, qwA, qbA));
            float bm = fmaxf(mx, l0);
            float sc = __expf(mx - bm), e0 = __expf(l0 - bm);
            ss = fmaf(ss, sc, e0);
            swa = fmaf(swa, sc, e0 * a0);
            ax = fmaf(ax, sc, e0 * bf2f(v0.x));
            ay = fmaf(ay, sc, e0 * bf2f(v0.y));
            mx = bm;
        }
        // val = (ax + swa*We + ss*be) / ss   (gives 0 for isolated nodes)
        float rcp = 1.f / fmaxf(ss, 1e-16f);
        float val0 = fmaf(swa, we2.x, fmaf(ss, be2.x, ax)) * rcp;
        float val1 = fmaf(swa, we2.y, fmaf(ss, be2.y, ay)) * rcp;
        float2 xr2 = *(const float2*)&xrb[(size_t)node * kHC + hc];
        float part = wb0 * val0 + wb1 * val1 + wb2 * xr2.x + wb3 * xr2.y
                   + wb4 * (val0 - xr2.x) + wb5 * (val1 - xr2.y);
#pragma unroll
        for (int s = 1; s < 64; s <<= 1) part += __shfl_xor(part, s);
        float beta = 1.f / (1.f + __expf(-part));
        float o0 = beta * xr2.x + (1.f - beta) * val0;
        float o1 = beta * xr2.y + (1.f - beta) * val1;
        oshS[wv][hc] = o0;
        oshS[wv][hc + 1] = o1;
        __builtin_amdgcn_wave_barrier();
        int c = lane & 31, half = lane >> 5;
        float hp = 0.f;
#pragma unroll
        for (int jj = 0; jj < 64; ++jj) {
            int j = half * 64 + jj;
            hp = fmaf(oshS[wv][j], wlS[j * kC + c], hp);
        }
        hp += __shfl_xor(hp, 32);
        if (lane < 32) hbuf[(size_t)node * kC + c] = fmaxf(hp + blc, 0.f);
        __builtin_amdgcn_wave_barrier();
    }
}

// ---------- 6) GraphNorm ----------
__global__ __launch_bounds__(256) void graphnorm_kernel(
    const float* __restrict__ hbuf, const int* __restrict__ batch,
    const float* __restrict__ gw, const float* __restrict__ gb,
    const float* __restrict__ gms, float* __restrict__ out)
{
    const int g = blockIdx.x;
    const int t = threadIdx.x;
    __shared__ int se[2];
    __shared__ float sums[8][kC];
    __shared__ float meansh[kC], rstdsh[kC];
    if (t < 2) {
        int target = g + t;
        int lo = 0, hi = kN;
        while (lo < hi) { int mid = (lo + hi) >> 1; if (batch[mid] < target) lo = mid + 1; else hi = mid; }
        se[t] = lo;
    }
    __syncthreads();
    int start = se[0], end = se[1];
    float cnt = fmaxf((float)(end - start), 1.f);
    int c = t & 31, r = t >> 5;
    float acc = 0.f;
    for (int n = start + r; n < end; n += 8) acc += hbuf[(size_t)n * kC + c];
    sums[r][c] = acc;
    __syncthreads();
    if (t < kC) {
        float s = 0.f;
#pragma unroll
        for (int i = 0; i < 8; ++i) s += sums[i][t];
        meansh[t] = s / cnt * gms[t];
    }
    __syncthreads();
    float msc = meansh[c];
    acc = 0.f;
    for (int n = start + r; n < end; n += 8) {
        float dd = hbuf[(size_t)n * kC + c] - msc;
        acc = fmaf(dd, dd, acc);
    }
    sums[r][c] = acc;
    __syncthreads();
    if (t < kC) {
        float s2 = 0.f;
#pragma unroll
        for (int i = 0; i < 8; ++i) s2 += sums[i][t];
        rstdsh[t] = rsqrtf(s2 / cnt + 1e-5f);
    }
    __syncthreads();
    float rstd = rstdsh[c], w = gw[c], b = gb[c];
    for (int n = start + r; n < end; n += 8) {
        float dd = hbuf[(size_t)n * kC + c] - msc;
        out[(size_t)n * kC + c] = fmaf(w * dd, rstd, b);
    }
}

extern "C" void kernel_launch(void* const* d_in, const int* in_sizes, int n_in,
                              void* d_out, int out_size, void* d_ws, size_t ws_size,
                              hipStream_t stream) {
    (void)in_sizes; (void)n_in; (void)out_size; (void)ws_size;
    const float* x     = (const float*)d_in[0];
    const int*   ei    = (const int*)d_in[1];
    const float* ea    = (const float*)d_in[2];
    const int*   batch = (const int*)d_in[3];
    const float* Wq    = (const float*)d_in[4];
    const float* bq    = (const float*)d_in[5];
    const float* Wk    = (const float*)d_in[6];
    const float* bk    = (const float*)d_in[7];
    const float* Wv    = (const float*)d_in[8];
    const float* bv    = (const float*)d_in[9];
    const float* We    = (const float*)d_in[10];
    const float* be    = (const float*)d_in[11];
    const float* Wskip = (const float*)d_in[12];
    const float* bskip = (const float*)d_in[13];
    const float* Wbeta = (const float*)d_in[14];
    const float* Wlin  = (const float*)d_in[15];
    const float* blin  = (const float*)d_in[16];
    const float* gw    = (const float*)d_in[17];
    const float* gb    = (const float*)d_in[18];
    const float* gms   = (const float*)d_in[19];
    float* out = (float*)d_out;

    char* ws = (char*)d_ws;
    const size_t NQ = (size_t)kN * kHC;
    int2*  csr    = (int2*)ws;            ws += (size_t)kE * 8;
    float* qb     = (float*)ws;           ws += NQ * 4;
    float* xrb    = (float*)ws;           ws += NQ * 4;
    unsigned short* kvb = (unsigned short*)ws; ws += (size_t)kN * 256 * 2;
    float* hbuf   = (float*)ws;           ws += (size_t)kN * kC * 4;
    int*   deg    = (int*)ws;             ws += (size_t)kN * 4;
    int*   cursor = (int*)ws;             ws += (size_t)kN * 4;
    int*   rowptr = (int*)ws;             ws += (size_t)(kN + 1) * 4;
    int*   bsum   = (int*)ws;             ws += (size_t)kNB * 4;
    int*   bofs   = (int*)ws;             ws += (size_t)kNB * 4;

    hipMemsetAsync(deg, 0, (size_t)kN * 4, stream);

    hist_kernel<<<(kE + 255) / 256, 256, 0, stream>>>(ei, deg);
    proj_kernel<<<(kN + 15) / 16, 512, 0, stream>>>(
        x, Wq, bq, Wk, bk, Wv, bv, Wskip, bskip, qb, kvb, xrb);
    scanA_kernel<<<kNB, 256, 0, stream>>>(deg, bsum);
    scanB_kernel<<<1, 256, 0, stream>>>(bsum, bofs, rowptr);
    scanC_kernel<<<kNB, 256, 0, stream>>>(deg, bofs, rowptr, cursor);
    scatter_kernel<<<(kE + 255) / 256, 256, 0, stream>>>(ei, ea, cursor, csr);
    node_attn_kernel<<<2048, 256, 0, stream>>>(
        rowptr, csr, qb, kvb, xrb, We, be, Wbeta, Wlin, blin, hbuf);
    graphnorm_kernel<<<kB, 256, 0, stream>>>(
        hbuf, batch, gw, gb, gms, out);
}

// Round 4
// 305.098 us; speedup vs baseline: 3.4300x; 1.2199x over previous
//
#include <hip/hip_runtime.h>
#include <math.h>

static constexpr int kN  = 50000;
static constexpr int kE  = 800000;
static constexpr int kC  = 32;
static constexpr int kH  = 4;
static constexpr int kHC = 128;   // H*C
static constexpr int kB  = 64;
static constexpr int kNB = (kN + 255) / 256;   // 196 scan blocks

__device__ __forceinline__ unsigned short f2bf(float f) {
    unsigned u = __float_as_uint(f);
    unsigned r = (u + 0x7FFFu + ((u >> 16) & 1u)) >> 16;
    return (unsigned short)r;
}

// ---------- 1) dense projections: q (f32), k|v interleaved bf16, x_r (f32) ----------
// kv row layout (256 ushorts): [k0,k1,v0,v1, k2,k3,v2,v3, ...] so lane l's
// uint2 load at offset 8l yields its two k and two v channels.
__global__ __launch_bounds__(512) void proj_kernel(
    const float* __restrict__ x,
    const float* __restrict__ Wq, const float* __restrict__ bq,
    const float* __restrict__ Wk, const float* __restrict__ bk,
    const float* __restrict__ Wv, const float* __restrict__ bv,
    const float* __restrict__ Wskip, const float* __restrict__ bskip,
    float* __restrict__ qb, unsigned short* __restrict__ kvb,
    float* __restrict__ xrb)
{
    __shared__ float4 xs[16][16];  // 16 nodes x 64 floats
    const int t  = threadIdx.x;
    const int n0 = blockIdx.x * 16;
    if (t < 256) {
        int nn = t >> 4, f4 = t & 15;
        int n = n0 + nn;
        float4 val = make_float4(0.f, 0.f, 0.f, 0.f);
        if (n < kN) val = ((const float4*)x)[(size_t)n * 16 + f4];
        xs[nn][f4] = val;
    }
    __syncthreads();
    const int mat = t >> 7;
    const int j   = t & 127;
    const float* W = (mat == 0) ? Wq : (mat == 1) ? Wk : (mat == 2) ? Wv : Wskip;
    const float* B = (mat == 0) ? bq : (mat == 1) ? bk : (mat == 2) ? bv : bskip;
    float acc[16];
    float bias = B[j];
#pragma unroll
    for (int n = 0; n < 16; ++n) acc[n] = bias;
#pragma unroll 4
    for (int ig = 0; ig < 16; ++ig) {
        float w0 = W[(ig * 4 + 0) * kHC + j];
        float w1 = W[(ig * 4 + 1) * kHC + j];
        float w2 = W[(ig * 4 + 2) * kHC + j];
        float w3 = W[(ig * 4 + 3) * kHC + j];
#pragma unroll
        for (int n = 0; n < 16; ++n) {
            float4 xv = xs[n][ig];
            acc[n] = fmaf(xv.x, w0, acc[n]);
            acc[n] = fmaf(xv.y, w1, acc[n]);
            acc[n] = fmaf(xv.z, w2, acc[n]);
            acc[n] = fmaf(xv.w, w3, acc[n]);
        }
    }
    const int kpos = ((j >> 1) << 2) | (j & 1);        // k channel j -> slot
    const int vpos = kpos | 2;                          // v channel j -> slot
#pragma unroll
    for (int n = 0; n < 16; ++n) {
        int nn = n0 + n;
        if (nn >= kN) continue;
        if (mat == 0)      qb[(size_t)nn * kHC + j] = acc[n];
        else if (mat == 1) kvb[(size_t)nn * 256 + kpos] = f2bf(acc[n]);
        else if (mat == 2) kvb[(size_t)nn * 256 + vpos] = f2bf(acc[n]);
        else               xrb[(size_t)nn * kHC + j] = acc[n];
    }
}

// ---------- 2) CSR: histogram ----------
__global__ __launch_bounds__(256) void hist_kernel(
    const int* __restrict__ ei, int* __restrict__ deg)
{
    int i = blockIdx.x * 256 + threadIdx.x;
    if (i < kE) atomicAdd(&deg[ei[kE + i]], 1);
}

// ---------- 3) CSR: hierarchical scan ----------
__global__ __launch_bounds__(256) void scanA_kernel(
    const int* __restrict__ deg, int* __restrict__ bsum)
{
    int i = blockIdx.x * 256 + threadIdx.x;
    int v = (i < kN) ? deg[i] : 0;
#pragma unroll
    for (int s = 1; s < 64; s <<= 1) v += __shfl_xor(v, s);
    __shared__ int sh[4];
    if ((threadIdx.x & 63) == 0) sh[threadIdx.x >> 6] = v;
    __syncthreads();
    if (threadIdx.x == 0) bsum[blockIdx.x] = sh[0] + sh[1] + sh[2] + sh[3];
}

__global__ __launch_bounds__(256) void scanB_kernel(
    const int* __restrict__ bsum, int* __restrict__ bofs, int* __restrict__ rowptr)
{
    __shared__ int sh[256];
    int t = threadIdx.x;
    int v = (t < kNB) ? bsum[t] : 0;
    sh[t] = v; __syncthreads();
    for (int off = 1; off < 256; off <<= 1) {
        int u = (t >= off) ? sh[t - off] : 0;
        __syncthreads();
        sh[t] += u;
        __syncthreads();
    }
    if (t < kNB) bofs[t] = sh[t] - v;
    if (t == kNB - 1) rowptr[kN] = sh[t];
}

__global__ __launch_bounds__(256) void scanC_kernel(
    const int* __restrict__ deg, const int* __restrict__ bofs,
    int* __restrict__ rowptr, int* __restrict__ cursor)
{
    __shared__ int sh[256];
    int t = threadIdx.x, i = blockIdx.x * 256 + t;
    int v = (i < kN) ? deg[i] : 0;
    sh[t] = v; __syncthreads();
    for (int off = 1; off < 256; off <<= 1) {
        int u = (t >= off) ? sh[t - off] : 0;
        __syncthreads();
        sh[t] += u;
        __syncthreads();
    }
    if (i < kN) {
        int ex = sh[t] - v + bofs[blockIdx.x];
        rowptr[i] = ex;
        cursor[i] = ex;
    }
}

// ---------- 4) CSR: scatter packed (src, edge_attr) ----------
__global__ __launch_bounds__(256) void scatter_kernel(
    const int* __restrict__ ei, const float* __restrict__ ea,
    int* __restrict__ cursor, int2* __restrict__ csr)
{
    int i = blockIdx.x * 256 + threadIdx.x;
    if (i >= kE) return;
    int dst = ei[kE + i];
    int slot = atomicAdd(&cursor[dst], 1);
    csr[slot] = make_int2(ei[i], __float_as_int(ea[i]));
}

// ---------- 5) per-node online-softmax attention + epilogue ----------
// one wave per node (static); lane l owns channels [2l,2l+1]; head = lane>>4
__global__ __launch_bounds__(256) void node_attn_kernel(
    const int* __restrict__ rowptr, const int2* __restrict__ csr,
    const float* __restrict__ qb, const unsigned short* __restrict__ kvb,
    const float* __restrict__ xrb,
    const float* __restrict__ We, const float* __restrict__ be,
    const float* __restrict__ Wbeta, const float* __restrict__ Wlin,
    const float* __restrict__ blin, float* __restrict__ hbuf)
{
    __shared__ float wlS[kHC * kC];   // 16 KB
    __shared__ float wbS[3 * kHC];
    __shared__ float oshS[4][kHC];
    const int t = threadIdx.x, wv = t >> 6, lane = t & 63;
    for (int i = t; i < kHC * kC; i += 256) wlS[i] = Wlin[i];
    for (int i = t; i < 3 * kHC; i += 256) wbS[i] = Wbeta[i];
    __syncthreads();

    const int node = blockIdx.x * 4 + wv;    // grid covers exactly kN
    const int hc = lane * 2;
    const float2 we2 = *(const float2*)&We[hc];
    const float2 be2 = *(const float2*)&be[hc];
    const float wb0 = wbS[hc], wb1 = wbS[hc + 1];
    const float wb2 = wbS[kHC + hc], wb3 = wbS[kHC + hc + 1];
    const float wb4 = wbS[2 * kHC + hc], wb5 = wbS[2 * kHC + hc + 1];
    const float blc = blin[lane & 31];
    const float A = 0.17677669529663687f;   // 1/sqrt(32)

    const float2 q2 = *(const float2*)&qb[(size_t)node * kHC + hc];
    float qw = q2.x * we2.x + q2.y * we2.y;
    float qe = q2.x * be2.x + q2.y * be2.y;
    qw += __shfl_xor(qw, 1); qe += __shfl_xor(qe, 1);
    qw += __shfl_xor(qw, 2); qe += __shfl_xor(qe, 2);
    qw += __shfl_xor(qw, 4); qe += __shfl_xor(qe, 4);
    qw += __shfl_xor(qw, 8); qe += __shfl_xor(qe, 8);
    const float qwA = qw * A, qbA = qe * A;

    float mx = -3.0e38f, ss = 0.f, swa = 0.f, ax = 0.f, ay = 0.f;
    const int beg = rowptr[node], end = rowptr[node + 1];
    int e = beg;
    for (; e + 3 < end; e += 4) {
        int2 c0 = csr[e], c1 = csr[e + 1], c2 = csr[e + 2], c3 = csr[e + 3];
        const uint2* r0 = (const uint2*)(kvb + (size_t)c0.x * 256);
        const uint2* r1 = (const uint2*)(kvb + (size_t)c1.x * 256);
        const uint2* r2 = (const uint2*)(kvb + (size_t)c2.x * 256);
        const uint2* r3 = (const uint2*)(kvb + (size_t)c3.x * 256);
        uint2 u0 = r0[lane], u1 = r1[lane], u2 = r2[lane], u3 = r3[lane];
        float a0 = __int_as_float(c0.y), a1 = __int_as_float(c1.y);
        float a2 = __int_as_float(c2.y), a3 = __int_as_float(c3.y);
        float p0 = fmaf(q2.y, __uint_as_float(u0.x & 0xFFFF0000u), q2.x * __uint_as_float(u0.x << 16));
        float p1 = fmaf(q2.y, __uint_as_float(u1.x & 0xFFFF0000u), q2.x * __uint_as_float(u1.x << 16));
        float p2 = fmaf(q2.y, __uint_as_float(u2.x & 0xFFFF0000u), q2.x * __uint_as_float(u2.x << 16));
        float p3 = fmaf(q2.y, __uint_as_float(u3.x & 0xFFFF0000u), q2.x * __uint_as_float(u3.x << 16));
        p0 += __shfl_xor(p0, 1); p1 += __shfl_xor(p1, 1); p2 += __shfl_xor(p2, 1); p3 += __shfl_xor(p3, 1);
        p0 += __shfl_xor(p0, 2); p1 += __shfl_xor(p1, 2); p2 += __shfl_xor(p2, 2); p3 += __shfl_xor(p3, 2);
        p0 += __shfl_xor(p0, 4); p1 += __shfl_xor(p1, 4); p2 += __shfl_xor(p2, 4); p3 += __shfl_xor(p3, 4);
        p0 += __shfl_xor(p0, 8); p1 += __shfl_xor(p1, 8); p2 += __shfl_xor(p2, 8); p3 += __shfl_xor(p3, 8);
        float l0 = fmaf(p0, A, fmaf(a0, qwA, qbA));
        float l1 = fmaf(p1, A, fmaf(a1, qwA, qbA));
        float l2 = fmaf(p2, A, fmaf(a2, qwA, qbA));
        float l3 = fmaf(p3, A, fmaf(a3, qwA, qbA));
        float bm = fmaxf(fmaxf(fmaxf(l0, l1), fmaxf(l2, l3)), mx);
        float sc = __expf(mx - bm);
        float e0 = __expf(l0 - bm), e1 = __expf(l1 - bm);
        float e2 = __expf(l2 - bm), e3 = __expf(l3 - bm);
        ss  = fmaf(ss , sc, (e0 + e1) + (e2 + e3));
        swa = fmaf(swa, sc, fmaf(e0, a0, fmaf(e1, a1, fmaf(e2, a2, e3 * a3))));
        ax  = fmaf(ax , sc, fmaf(e0, __uint_as_float(u0.y << 16),
                          fmaf(e1, __uint_as_float(u1.y << 16),
                          fmaf(e2, __uint_as_float(u2.y << 16),
                               e3 * __uint_as_float(u3.y << 16)))));
        ay  = fmaf(ay , sc, fmaf(e0, __uint_as_float(u0.y & 0xFFFF0000u),
                          fmaf(e1, __uint_as_float(u1.y & 0xFFFF0000u),
                          fmaf(e2, __uint_as_float(u2.y & 0xFFFF0000u),
                               e3 * __uint_as_float(u3.y & 0xFFFF0000u)))));
        mx = bm;
    }
    for (; e < end; ++e) {
        int2 c0 = csr[e];
        const uint2* r0 = (const uint2*)(kvb + (size_t)c0.x * 256);
        uint2 u0 = r0[lane];
        float a0 = __int_as_float(c0.y);
        float p0 = fmaf(q2.y, __uint_as_float(u0.x & 0xFFFF0000u), q2.x * __uint_as_float(u0.x << 16));
        p0 += __shfl_xor(p0, 1); p0 += __shfl_xor(p0, 2);
        p0 += __shfl_xor(p0, 4); p0 += __shfl_xor(p0, 8);
        float l0 = fmaf(p0, A, fmaf(a0, qwA, qbA));
        float bm = fmaxf(mx, l0);
        float sc = __expf(mx - bm), e0 = __expf(l0 - bm);
        ss  = fmaf(ss , sc, e0);
        swa = fmaf(swa, sc, e0 * a0);
        ax  = fmaf(ax , sc, e0 * __uint_as_float(u0.y << 16));
        ay  = fmaf(ay , sc, e0 * __uint_as_float(u0.y & 0xFFFF0000u));
        mx = bm;
    }
    // val = (ax + swa*We + ss*be) / ss   (0 for isolated nodes)
    float rcp = 1.f / fmaxf(ss, 1e-16f);
    float val0 = fmaf(swa, we2.x, fmaf(ss, be2.x, ax)) * rcp;
    float val1 = fmaf(swa, we2.y, fmaf(ss, be2.y, ay)) * rcp;
    float2 xr2 = *(const float2*)&xrb[(size_t)node * kHC + hc];
    float part = wb0 * val0 + wb1 * val1 + wb2 * xr2.x + wb3 * xr2.y
               + wb4 * (val0 - xr2.x) + wb5 * (val1 - xr2.y);
#pragma unroll
    for (int s = 1; s < 64; s <<= 1) part += __shfl_xor(part, s);
    float beta = 1.f / (1.f + __expf(-part));
    float o0 = beta * xr2.x + (1.f - beta) * val0;
    float o1 = beta * xr2.y + (1.f - beta) * val1;
    oshS[wv][hc] = o0;
    oshS[wv][hc + 1] = o1;
    __builtin_amdgcn_wave_barrier();
    int c = lane & 31, half = lane >> 5;
    float hp = 0.f;
#pragma unroll
    for (int jj = 0; jj < 64; ++jj) {
        int j = half * 64 + jj;
        hp = fmaf(oshS[wv][j], wlS[j * kC + c], hp);
    }
    hp += __shfl_xor(hp, 32);
    if (lane < 32) hbuf[(size_t)node * kC + c] = fmaxf(hp + blc, 0.f);
}

// ---------- 6a) GraphNorm stats: one block per graph, single pass ----------
__global__ __launch_bounds__(256) void gn_reduce_kernel(
    const float* __restrict__ hbuf, const int* __restrict__ batch,
    const float* __restrict__ gms, float* __restrict__ stats)
{
    const int g = blockIdx.x;
    const int t = threadIdx.x;
    __shared__ int se[2];
    __shared__ float s1[8][kC], s2[8][kC];
    if (t < 2) {
        int target = g + t;
        int lo = 0, hi = kN;
        while (lo < hi) { int mid = (lo + hi) >> 1; if (batch[mid] < target) lo = mid + 1; else hi = mid; }
        se[t] = lo;
    }
    __syncthreads();
    int start = se[0], end = se[1];
    float cnt = fmaxf((float)(end - start), 1.f);
    int c = t & 31, r = t >> 5;
    float a = 0.f, b = 0.f;
    for (int n = start + r; n < end; n += 8) {
        float v = hbuf[(size_t)n * kC + c];
        a += v; b = fmaf(v, v, b);
    }
    s1[r][c] = a; s2[r][c] = b;
    __syncthreads();
    if (t < kC) {
        float sa = 0.f, sb = 0.f;
#pragma unroll
        for (int i = 0; i < 8; ++i) { sa += s1[i][t]; sb += s2[i][t]; }
        float mean = sa / cnt;
        float ms   = mean * gms[t];
        float var  = sb / cnt - 2.f * ms * mean + ms * ms;
        stats[g * 64 + t]      = ms;
        stats[g * 64 + 32 + t] = rsqrtf(var + 1e-5f);
    }
}

// ---------- 6b) GraphNorm apply: fully parallel ----------
__global__ __launch_bounds__(256) void gn_apply_kernel(
    const float* __restrict__ hbuf, const int* __restrict__ batch,
    const float* __restrict__ stats,
    const float* __restrict__ gw, const float* __restrict__ gb,
    float* __restrict__ out)
{
    int idx = blockIdx.x * 256 + threadIdx.x;
    if (idx >= kN * kC) return;
    int n = idx >> 5, c = idx & 31;
    int g = batch[n];
    float ms   = stats[g * 64 + c];
    float rstd = stats[g * 64 + 32 + c];
    float v = hbuf[idx];
    out[idx] = fmaf(gw[c] * (v - ms), rstd, gb[c]);
}

extern "C" void kernel_launch(void* const* d_in, const int* in_sizes, int n_in,
                              void* d_out, int out_size, void* d_ws, size_t ws_size,
                              hipStream_t stream) {
    (void)in_sizes; (void)n_in; (void)out_size; (void)ws_size;
    const float* x     = (const float*)d_in[0];
    const int*   ei    = (const int*)d_in[1];
    const float* ea    = (const float*)d_in[2];
    const int*   batch = (const int*)d_in[3];
    const float* Wq    = (const float*)d_in[4];
    const float* bq    = (const float*)d_in[5];
    const float* Wk    = (const float*)d_in[6];
    const float* bk    = (const float*)d_in[7];
    const float* Wv    = (const float*)d_in[8];
    const float* bv    = (const float*)d_in[9];
    const float* We    = (const float*)d_in[10];
    const float* be    = (const float*)d_in[11];
    const float* Wskip = (const float*)d_in[12];
    const float* bskip = (const float*)d_in[13];
    const float* Wbeta = (const float*)d_in[14];
    const float* Wlin  = (const float*)d_in[15];
    const float* blin  = (const float*)d_in[16];
    const float* gw    = (const float*)d_in[17];
    const float* gb    = (const float*)d_in[18];
    const float* gms   = (const float*)d_in[19];
    float* out = (float*)d_out;

    char* ws = (char*)d_ws;
    const size_t NQ = (size_t)kN * kHC;
    int2*  csr    = (int2*)ws;            ws += (size_t)kE * 8;
    float* qb     = (float*)ws;           ws += NQ * 4;
    float* xrb    = (float*)ws;           ws += NQ * 4;
    unsigned short* kvb = (unsigned short*)ws; ws += (size_t)kN * 256 * 2;
    float* hbuf   = (float*)ws;           ws += (size_t)kN * kC * 4;
    int*   deg    = (int*)ws;             ws += (size_t)kN * 4;
    int*   cursor = (int*)ws;             ws += (size_t)kN * 4;
    int*   rowptr = (int*)ws;             ws += (size_t)(kN + 1) * 4;
    int*   bsum   = (int*)ws;             ws += (size_t)kNB * 4;
    int*   bofs   = (int*)ws;             ws += (size_t)kNB * 4;
    float* stats  = (float*)ws;           ws += (size_t)kB * 64 * 4;

    hipMemsetAsync(deg, 0, (size_t)kN * 4, stream);

    hist_kernel<<<(kE + 255) / 256, 256, 0, stream>>>(ei, deg);
    proj_kernel<<<(kN + 15) / 16, 512, 0, stream>>>(
        x, Wq, bq, Wk, bk, Wv, bv, Wskip, bskip, qb, kvb, xrb);
    scanA_kernel<<<kNB, 256, 0, stream>>>(deg, bsum);
    scanB_kernel<<<1, 256, 0, stream>>>(bsum, bofs, rowptr);
    scanC_kernel<<<kNB, 256, 0, stream>>>(deg, bofs, rowptr, cursor);
    scatter_kernel<<<(kE + 255) / 256, 256, 0, stream>>>(ei, ea, cursor, csr);
    node_attn_kernel<<<kN / 4, 256, 0, stream>>>(
        rowptr, csr, qb, kvb, xrb, We, be, Wbeta, Wlin, blin, hbuf);
    gn_reduce_kernel<<<kB, 256, 0, stream>>>(hbuf, batch, gms, stats);
    gn_apply_kernel<<<(kN * kC + 255) / 256, 256, 0, stream>>>(
        hbuf, batch, stats, gw, gb, out);
}